// Round 7
// baseline (501.310 us; speedup 1.0000x reference)
//
#include <hip/hip_runtime.h>
#include <hip/hip_bf16.h>

// Int8Linear: out[B,T,OUT] = x[B,T,IN] @ (w_int8*scale)^T + bias
// M = B*T = 8192, N = OUT = 11008, K = IN = 4096
// Full-int8: x per-token absmax-quantized, W exact i8,
// mfma_i32_32x32x32_i8, exact i32 accum, epilogue acc*xs[m]*wscale[n]+bias.
// R7: K-split software pipeline — each MFMA cluster's frags are read under
// the previous cluster (S0/S1 rotation, no extra regs); 32x32x32 shape
// (+12% peak, half the issue slots); ring-4 LDS, stage T+3, formal vmcnt
// before each barrier.
#define MDIM 8192
#define NDIM 11008
#define KDIM 4096

#define BM 256
#define BN 256
#define BK 64
#define NT (KDIM / BK)   // 64 K-tiles

typedef __attribute__((ext_vector_type(4)))  int   int4v;
typedef __attribute__((ext_vector_type(16))) int   int16v;

// ---------------- x quantization: per-token absmax -> i8 ----------------

__global__ __launch_bounds__(256) void quant_x_kernel(const float* __restrict__ x,
                                                      int* __restrict__ q,
                                                      float* __restrict__ xs) {
  int row = blockIdx.x;
  int tid = threadIdx.x;
  const float4* xr = (const float4*)(x + (size_t)row * KDIM);
  float4 v[4];
  float amax = 0.f;
#pragma unroll
  for (int i = 0; i < 4; ++i) {
    v[i] = xr[tid + i * 256];
    amax = fmaxf(amax, fmaxf(fmaxf(fabsf(v[i].x), fabsf(v[i].y)),
                             fmaxf(fabsf(v[i].z), fabsf(v[i].w))));
  }
#pragma unroll
  for (int off = 32; off; off >>= 1)
    amax = fmaxf(amax, __shfl_xor(amax, off));
  __shared__ float smax[4];
  if ((tid & 63) == 0) smax[tid >> 6] = amax;
  __syncthreads();
  amax = fmaxf(fmaxf(smax[0], smax[1]), fmaxf(smax[2], smax[3]));
  amax = fmaxf(amax, 1e-20f);
  float inv = 127.f / amax;
  if (tid == 0) xs[row] = amax * (1.f / 127.f);
  int* qr = q + (size_t)row * (KDIM / 4);
#pragma unroll
  for (int i = 0; i < 4; ++i) {
    int a = (int)rintf(v[i].x * inv) & 255;
    int b = (int)rintf(v[i].y * inv) & 255;
    int c = (int)rintf(v[i].z * inv) & 255;
    int d = (int)rintf(v[i].w * inv);
    qr[tid + i * 256] = a | (b << 8) | (c << 16) | (d << 24);
  }
}

// ---------------- W pack: int32 -> i8 (exact) ----------------

__global__ void cvt_w_kernel(const int* __restrict__ w, int* __restrict__ q, int n) {
  int stride = gridDim.x * blockDim.x;
  for (int i = blockIdx.x * blockDim.x + threadIdx.x; i < n; i += stride) {
    int4v v = *(const int4v*)(w + (size_t)i * 4);
    q[i] = (v.x & 255) | ((v.y & 255) << 8) | ((v.z & 255) << 16) | (v.w << 24);
  }
}

// ---------------- 256x256 int8 MFMA GEMM (32x32x32, K-split pipeline) ----
// LDS: per operand [4-ring][256 rows][64 B] = 64 KB; total 128 KB.
// Swizzle: LDS granule g of row r holds source k-granule g ^ key(r),
// key(r) = ((r>>1)&3) ^ ((r>>3)&3)  (spreads 32-row b128 reads, 2-way max).
// Tile T: {read S1<-(T,k1) | stage A(T+3)} MFMA(S0) {read S0<-(T+1,k0) |
//          stage B(T+3)} MFMA(S1) vmcnt(4) barrier.

#define SBARR() __builtin_amdgcn_sched_barrier(0)
#define BARR()  __builtin_amdgcn_s_barrier()
#define VMW_(n) asm volatile("s_waitcnt vmcnt(" #n ")" ::: "memory")
#define VMW(n)  VMW_(n)

#define GLL(SRC, DST) \
  __builtin_amdgcn_global_load_lds( \
      (const __attribute__((address_space(1))) void*)(SRC), \
      (__attribute__((address_space(3))) void*)(DST), 16, 0, 0)

// stage one operand's K-tile T (16KB): 2 loads/thread, linear LDS dest
#define STAGE(GSRC, LBASE, BUFI, T) do { \
    const char* _s = (GSRC) + (T) * 64; \
    GLL(_s, (LBASE) + (BUFI) * 16384 + w * 1024); \
    GLL(_s + rstep, (LBASE) + (BUFI) * 16384 + w * 1024 + 8192); \
  } while (0)

// swizzled fragment read (16B = 16 i8): row = RBASE + (lane&31), k-gran per koff
#define RD32(LB, SLOT, RBASE, KB) \
  (*(const int4v*)((LB) + (SLOT) * 16384 + ((RBASE) + ln31) * 64 + (KB)))

#define CL(AA, BB) do { \
    _Pragma("unroll") for (int mt = 0; mt < 4; ++mt) \
    _Pragma("unroll") for (int nt = 0; nt < 2; ++nt) \
      acc[mt * 2 + nt] = __builtin_amdgcn_mfma_i32_32x32x32_i8( \
          AA[mt], BB[nt], acc[mt * 2 + nt], 0, 0, 0); \
  } while (0)

// One K-tile. SLT = ring slot (T&3). SD: stage T+3. EN: vmcnt at end.
// PF: prefetch S0 <- (T+1, k0). LASTT: skip trailing wait+barrier.
#define KT(T, SLT, SD, EN, PF, LASTT) do { \
    _Pragma("unroll") for (int mt = 0; mt < 4; ++mt) aS1[mt] = RD32(ldsA, SLT, arow + mt * 32, koff1); \
    _Pragma("unroll") for (int nt = 0; nt < 2; ++nt) bS1[nt] = RD32(ldsB, SLT, bcolr + nt * 32, koff1); \
    if (SD) STAGE(gAs, ldsA, ((SLT) + 3) & 3, (T) + 3); \
    SBARR(); \
    __builtin_amdgcn_s_setprio(1); CL(aS0, bS0); __builtin_amdgcn_s_setprio(0); \
    SBARR(); \
    if (PF) { \
      _Pragma("unroll") for (int mt = 0; mt < 4; ++mt) aS0[mt] = RD32(ldsA, ((SLT) + 1) & 3, arow + mt * 32, koff0); \
      _Pragma("unroll") for (int nt = 0; nt < 2; ++nt) bS0[nt] = RD32(ldsB, ((SLT) + 1) & 3, bcolr + nt * 32, koff0); \
    } \
    if (SD) STAGE(gBs, ldsB, ((SLT) + 3) & 3, (T) + 3); \
    SBARR(); \
    __builtin_amdgcn_s_setprio(1); CL(aS1, bS1); __builtin_amdgcn_s_setprio(0); \
    SBARR(); \
    if (!(LASTT)) { VMW(EN); BARR(); SBARR(); } \
  } while (0)

__global__ __launch_bounds__(512, 2) void gemm_i8_kernel(
    const char* __restrict__ A,
    const char* __restrict__ Bt,
    const float* __restrict__ xs,
    const float* __restrict__ scale,
    const float* __restrict__ bias,
    float* __restrict__ C)
{
  __shared__ __attribute__((aligned(16))) char As[4][256][64];  // 64 KB
  __shared__ __attribute__((aligned(16))) char Bs[4][256][64];  // 64 KB

  const int nbc = NDIM / BN;  // 43 ; grid = 32*43 = 1376 = 8*172
  int bid = blockIdx.x;
  int cpx = gridDim.x >> 3;
  int swz = (bid & 7) * cpx + (bid >> 3);   // bijective XCD swizzle
  int brow = (swz / nbc) * BM;              // row-major within chunk
  int bcol = (swz % nbc) * BN;

  int tid  = threadIdx.x;
  int lane = tid & 63;
  int w    = tid >> 6;
  int wr   = (w >> 2) & 1;   // M-wave (2)
  int wc   = w & 3;          // N-wave (4)

  int ln31 = lane & 31;
  int hi   = lane >> 5;
  // read-side swizzle: key(row) = ((row>>1)&3)^((row>>3)&3); row bits 1-4 = ln31 bits
  int keyl  = ((lane >> 1) & 3) ^ ((lane >> 3) & 3);
  int koff0 = ((hi ^ keyl) << 4);        // k-step 0 granule byte
  int koff1 = koff0 ^ 32;                // k-step 1 (granule +2)

  int arow  = wr * 128;                  // wave's A base row
  int bcolr = wc * 64;                   // wave's B base row

  // staging: thread granule g = w*64+lane -> row srow = w*16 + lane/4,
  // dst granule lane&3; inverse-swizzled source k-granule:
  int srow_key = ((lane >> 3) & 3) ^ ((2 * w + (lane >> 5)) & 3);
  int csrc = (lane & 3) ^ srow_key;
  int srow = w * 16 + (lane >> 2);
  const char* gAs = A  + (size_t)(brow + srow) * KDIM + csrc * 16;
  const char* gBs = Bt + (size_t)(bcol + srow) * KDIM + csrc * 16;
  const size_t rstep = (size_t)128 * KDIM;

  char* ldsA = &As[0][0][0];
  char* ldsB = &Bs[0][0][0];

  int16v acc[8] = {};
  int4v aS0[4], bS0[2], aS1[4], bS1[2];

  // prologue: stage tiles 0,1,2 into slots 0,1,2 (12 loads/thread);
  // vmcnt(4): tiles 0 AND 1 landed (for tile-0 reads and tile-0's PF of 1)
  STAGE(gAs, ldsA, 0, 0);  STAGE(gBs, ldsB, 0, 0);
  STAGE(gAs, ldsA, 1, 1);  STAGE(gBs, ldsB, 1, 1);
  STAGE(gAs, ldsA, 2, 2);  STAGE(gBs, ldsB, 2, 2);
  VMW(4); BARR(); SBARR();

  // S0 <- (0, k0)
#pragma unroll
  for (int mt = 0; mt < 4; ++mt) aS0[mt] = RD32(ldsA, 0, arow + mt * 32, koff0);
#pragma unroll
  for (int nt = 0; nt < 2; ++nt) bS0[nt] = RD32(ldsB, 0, bcolr + nt * 32, koff0);

  // steady: tiles 0..59 stage T+3, end-wait vmcnt(4) (=> T+2 landed)
  for (int t = 0; t < 60; t += 4) {
    KT(t,     0, 1, 4, 1, 0);
    KT(t + 1, 1, 1, 4, 1, 0);
    KT(t + 2, 2, 1, 4, 1, 0);
    KT(t + 3, 3, 1, 4, 1, 0);
  }
  KT(60, 0, 1, 4, 1, 0);   // stages 63
  KT(61, 1, 0, 0, 1, 0);   // drain: 63 landed for 62's PF
  KT(62, 2, 0, 0, 1, 0);
  KT(63, 3, 0, 0, 0, 1);   // last: no PF, no trailing wait

  // epilogue: 32x32 C/D layout col = lane&31, row = (reg&3)+8*(reg>>2)+4*hi
  int col0  = bcol + wc * 64 + ln31;
  int rbase = brow + wr * 128 + 4 * hi;
#pragma unroll
  for (int mt = 0; mt < 4; ++mt) {
#pragma unroll
    for (int r = 0; r < 16; ++r) {
      int rg = rbase + mt * 32 + (r & 3) + 8 * (r >> 2);
      float xv = xs[rg];
#pragma unroll
      for (int nt = 0; nt < 2; ++nt) {
        int ng = col0 + nt * 32;
        __builtin_nontemporal_store(
            (float)acc[mt * 2 + nt][r] * (xv * scale[ng]) + bias[ng],
            &C[(size_t)rg * NDIM + ng]);
      }
    }
  }
}

// ---------------- fallback (only if d_ws is too small) ----------------

__global__ void naive_kernel(const float* __restrict__ x, const int* __restrict__ w,
                             const float* __restrict__ scale, const float* __restrict__ bias,
                             float* __restrict__ out)
{
  int n = blockIdx.x * blockDim.x + threadIdx.x;
  int m = blockIdx.y;
  if (n >= NDIM) return;
  const float* xr = x + (size_t)m * KDIM;
  const int* wrow = w + (size_t)n * KDIM;
  float s = 0.f;
  for (int k = 0; k < KDIM; ++k) s += xr[k] * (float)wrow[k];
  out[(size_t)m * NDIM + n] = s * scale[n] + bias[n];
}

// ---------------- launcher ----------------

extern "C" void kernel_launch(void* const* d_in, const int* in_sizes, int n_in,
                              void* d_out, int out_size, void* d_ws, size_t ws_size,
                              hipStream_t stream) {
  const float* x      = (const float*)d_in[0];
  const int*   w8     = (const int*)d_in[1];
  const float* wscale = (const float*)d_in[2];
  const float* bias   = (const float*)d_in[3];
  float* out = (float*)d_out;

  size_t aq = (size_t)MDIM * KDIM;   // 33.5 MB i8
  size_t bq = (size_t)NDIM * KDIM;   // 45.1 MB i8
  size_t xb = (size_t)MDIM * 4;      // 32 KB scales

  if (ws_size >= aq + bq + xb) {
    char* Aq = (char*)d_ws;
    char* Bq = (char*)d_ws + aq;
    float* xsp = (float*)((char*)d_ws + aq + bq);
    quant_x_kernel<<<MDIM, 256, 0, stream>>>(x, (int*)Aq, xsp);
    cvt_w_kernel<<<2048, 256, 0, stream>>>(w8, (int*)Bq, NDIM * KDIM / 4);
    gemm_i8_kernel<<<(MDIM / BM) * (NDIM / BN), 512, 0, stream>>>(
        Aq, Bq, xsp, wscale, bias, out);
  } else {
    naive_kernel<<<dim3((NDIM + 255) / 256, MDIM), 256, 0, stream>>>(x, w8, wscale, bias, out);
  }
}

// Round 8
// 491.986 us; speedup vs baseline: 1.0190x; 1.0190x over previous
//
#include <hip/hip_runtime.h>
#include <hip/hip_bf16.h>

// Int8Linear: out[B,T,OUT] = x[B,T,IN] @ (w_int8*scale)^T + bias
// M = B*T = 8192, N = OUT = 11008, K = IN = 4096
// Full-int8: x per-token absmax-quantized, W exact i8, mfma_i32_16x16x64_i8,
// exact i32 accum, epilogue acc*xs[m]*wscale[n]+bias.
// R8: R6's PROVEN 0-conflict LDS geometry (16-row frags, quarter-wave
// k-spread) + ring-4 pipeline where ALL of tile T+1's 12 fragment reads
// execute inside tile T's two MFMA shadows (PF1/PF2). No dependent ds_read
// at any cluster boundary; all lgkm waits are counted. E/O register-name
// rotation (no copies, static indexing).
#define MDIM 8192
#define NDIM 11008
#define KDIM 4096

#define BM 256
#define BN 256
#define BK 64
#define NT (KDIM / BK)   // 64 K-tiles

typedef __attribute__((ext_vector_type(4))) int int4v;

// ---------------- x quantization: per-token absmax -> i8 ----------------

__global__ __launch_bounds__(256) void quant_x_kernel(const float* __restrict__ x,
                                                      int* __restrict__ q,
                                                      float* __restrict__ xs) {
  int row = blockIdx.x;
  int tid = threadIdx.x;
  const float4* xr = (const float4*)(x + (size_t)row * KDIM);
  float4 v[4];
  float amax = 0.f;
#pragma unroll
  for (int i = 0; i < 4; ++i) {
    v[i] = xr[tid + i * 256];
    amax = fmaxf(amax, fmaxf(fmaxf(fabsf(v[i].x), fabsf(v[i].y)),
                             fmaxf(fabsf(v[i].z), fabsf(v[i].w))));
  }
#pragma unroll
  for (int off = 32; off; off >>= 1)
    amax = fmaxf(amax, __shfl_xor(amax, off));
  __shared__ float smax[4];
  if ((tid & 63) == 0) smax[tid >> 6] = amax;
  __syncthreads();
  amax = fmaxf(fmaxf(smax[0], smax[1]), fmaxf(smax[2], smax[3]));
  amax = fmaxf(amax, 1e-20f);
  float inv = 127.f / amax;
  if (tid == 0) xs[row] = amax * (1.f / 127.f);
  int* qr = q + (size_t)row * (KDIM / 4);
#pragma unroll
  for (int i = 0; i < 4; ++i) {
    int a = (int)rintf(v[i].x * inv) & 255;
    int b = (int)rintf(v[i].y * inv) & 255;
    int c = (int)rintf(v[i].z * inv) & 255;
    int d = (int)rintf(v[i].w * inv);
    qr[tid + i * 256] = a | (b << 8) | (c << 16) | (d << 24);
  }
}

// ---------------- W pack: int32 -> i8 (exact) ----------------

__global__ void cvt_w_kernel(const int* __restrict__ w, int* __restrict__ q, int n) {
  int stride = gridDim.x * blockDim.x;
  for (int i = blockIdx.x * blockDim.x + threadIdx.x; i < n; i += stride) {
    int4v v = *(const int4v*)(w + (size_t)i * 4);
    q[i] = (v.x & 255) | ((v.y & 255) << 8) | ((v.z & 255) << 16) | (v.w << 24);
  }
}

// ---------------- 256x256 int8 MFMA GEMM (ring-4, full PF pipeline) ------
// LDS: per operand [4-ring][256 rows][64 B] = 64 KB; total 128 KB.
// Invariant entering tile T: slots T,T+1 landed+barriered; [A(T+2),B(T+2)]
// outstanding. Tile T: {PF (T+1).af2 | stage A(T+3)} CL1 {PF (T+1).af/bf |
// stage B(T+3)} CL2 vmcnt(4) barrier.

#define SBARR() __builtin_amdgcn_sched_barrier(0)
#define BARR()  __builtin_amdgcn_s_barrier()
#define VMW_(n) asm volatile("s_waitcnt vmcnt(" #n ")" ::: "memory")
#define VMW(n)  VMW_(n)

#define GLL(SRC, DST) \
  __builtin_amdgcn_global_load_lds( \
      (const __attribute__((address_space(1))) void*)(SRC), \
      (__attribute__((address_space(3))) void*)(DST), 16, 0, 0)

// stage one operand's K-tile T (16KB): 2 loads/thread, linear LDS dest
#define STAGE(GSRC, LBASE, BUFI, T) do { \
    const char* _s = (GSRC) + (T) * 64; \
    GLL(_s, (LBASE) + (BUFI) * 16384 + w * 1024); \
    GLL(_s + rstep, (LBASE) + (BUFI) * 16384 + w * 1024 + 8192); \
  } while (0)

// swizzled fragment read (16B = 16 i8 along K for one row) — R6 geometry
#define RD(LB, BUFI, ROW) \
  (*(const int4v*)((LB) + (BUFI) * 16384 + (ROW) * 64 + kbs))

#define MFMA16(AF, BF, MOFF) do { \
    _Pragma("unroll") for (int mi = 0; mi < 4; ++mi) \
    _Pragma("unroll") for (int ni = 0; ni < 4; ++ni) \
      acc[(MOFF) + mi][ni] = __builtin_amdgcn_mfma_i32_16x16x64_i8( \
          AF[mi], BF[ni], acc[(MOFF) + mi][ni], 0, 0, 0); \
  } while (0)

// One K-tile. SLT = T&3 (compile-time). C* = current frags (tile T),
// N* = next frags filled for tile T+1. SD: stage T+3. EN: vmcnt at end.
// PF: prefetch (T+1) frags. LASTT: skip trailing wait+barrier.
#define KT(T, SLT, CA, CA2, CB, NA, NA2, NB, SD, EN, PF, LASTT) do { \
    if (PF) { \
      _Pragma("unroll") for (int mi = 0; mi < 4; ++mi) \
        NA2[mi] = RD(ldsA, ((SLT) + 1) & 3, arow0 + 64 + mi * 16); \
    } \
    if (SD) STAGE(gAs, ldsA, ((SLT) + 3) & 3, (T) + 3); \
    SBARR(); \
    __builtin_amdgcn_s_setprio(1); MFMA16(CA, CB, 0); __builtin_amdgcn_s_setprio(0); \
    SBARR(); \
    if (PF) { \
      _Pragma("unroll") for (int mi = 0; mi < 4; ++mi) \
        NA[mi] = RD(ldsA, ((SLT) + 1) & 3, arow0 + mi * 16); \
      _Pragma("unroll") for (int ni = 0; ni < 4; ++ni) \
        NB[ni] = RD(ldsB, ((SLT) + 1) & 3, brow0 + ni * 16); \
    } \
    if (SD) STAGE(gBs, ldsB, ((SLT) + 3) & 3, (T) + 3); \
    SBARR(); \
    __builtin_amdgcn_s_setprio(1); MFMA16(CA2, CB, 4); __builtin_amdgcn_s_setprio(0); \
    SBARR(); \
    if (!(LASTT)) { VMW(EN); BARR(); SBARR(); } \
  } while (0)

__global__ __launch_bounds__(512, 2) void gemm_i8_kernel(
    const char* __restrict__ A,
    const char* __restrict__ Bt,
    const float* __restrict__ xs,
    const float* __restrict__ scale,
    const float* __restrict__ bias,
    float* __restrict__ C)
{
  __shared__ __attribute__((aligned(16))) char As[4][256][64];  // 64 KB
  __shared__ __attribute__((aligned(16))) char Bs[4][256][64];  // 64 KB

  const int nbc = NDIM / BN;  // 43 ; grid = 32*43 = 1376 = 8*172
  int bid = blockIdx.x;
  int cpx = gridDim.x >> 3;
  int swz = (bid & 7) * cpx + (bid >> 3);   // bijective XCD swizzle
  int brow = (swz / nbc) * BM;              // row-major within chunk
  int bcol = (swz % nbc) * BN;

  int tid  = threadIdx.x;
  int lane = tid & 63;
  int w    = tid >> 6;
  int wr   = (w >> 2) & 1;   // M-wave (2)
  int wc   = w & 3;          // N-wave (4)

  int ra = lane & 15;                         // fragment row within 16
  int kb = (lane >> 4) * 16;                  // byte offset along K (64B row)
  int kbs = kb ^ (((ra >> 1) & 3) << 4);      // proven 0-conflict swizzle

  int arow0 = wr * 128 + ra;                  // wave's A base row + frag row
  int brow0 = wc * 64 + ra;                   // wave's B base row + frag row

  // staging: thread granule g = w*64+lane -> (row srow, dst granule lane&3);
  // inverse-swizzled source k-granule (lane-constant)
  int srow = w * 16 + (lane >> 2);
  int csrc = (lane & 3) ^ ((lane >> 3) & 3);
  const char* gAs = A  + (size_t)(brow + srow) * KDIM + csrc * 16;
  const char* gBs = Bt + (size_t)(bcol + srow) * KDIM + csrc * 16;
  const size_t rstep = (size_t)128 * KDIM;

  char* ldsA = &As[0][0][0];
  char* ldsB = &Bs[0][0][0];

  int4v acc[8][4] = {};
  int4v afE[4], af2E[4], bfE[4];   // even-tile current set
  int4v afO[4], af2O[4], bfO[4];   // odd-tile current set

  // prologue: stage tiles 0,1,2 into slots 0,1,2 (12 loads/thread);
  // vmcnt(4) -> tiles 0,1 landed ([A2,B2] in flight)
  STAGE(gAs, ldsA, 0, 0);  STAGE(gBs, ldsB, 0, 0);
  STAGE(gAs, ldsA, 1, 1);  STAGE(gBs, ldsB, 1, 1);
  STAGE(gAs, ldsA, 2, 2);  STAGE(gBs, ldsB, 2, 2);
  VMW(4); BARR(); SBARR();

  // pre-read tile 0 frags into E set (only exposed reads in the kernel)
#pragma unroll
  for (int mi = 0; mi < 4; ++mi) afE[mi]  = RD(ldsA, 0, arow0 + mi * 16);
#pragma unroll
  for (int mi = 0; mi < 4; ++mi) af2E[mi] = RD(ldsA, 0, arow0 + 64 + mi * 16);
#pragma unroll
  for (int ni = 0; ni < 4; ++ni) bfE[ni]  = RD(ldsB, 0, brow0 + ni * 16);

  // steady: tiles 0..59 (stage T+3, PF T+1, vmcnt(4))
  for (int t = 0; t < 60; t += 4) {
    KT(t,     0, afE, af2E, bfE, afO, af2O, bfO, 1, 4, 1, 0);
    KT(t + 1, 1, afO, af2O, bfO, afE, af2E, bfE, 1, 4, 1, 0);
    KT(t + 2, 2, afE, af2E, bfE, afO, af2O, bfO, 1, 4, 1, 0);
    KT(t + 3, 3, afO, af2O, bfO, afE, af2E, bfE, 1, 4, 1, 0);
  }
  // tail: 60 stages 63; 61 drains to 0 (63 must land for 62's PF); 63 no PF
  KT(60, 0, afE, af2E, bfE, afO, af2O, bfO, 1, 4, 1, 0);
  KT(61, 1, afO, af2O, bfO, afE, af2E, bfE, 0, 0, 1, 0);
  KT(62, 2, afE, af2E, bfE, afO, af2O, bfO, 0, 0, 1, 0);
  KT(63, 3, afO, af2O, bfO, afE, af2E, bfE, 0, 0, 0, 1);

  // epilogue: C/D layout col = lane&15, row = (lane>>4)*4 + reg (dtype-indep)
  // non-temporal stores: write stream must not churn L2/L3
  int col0 = bcol + wc * 64 + ra;
  int row0 = brow + wr * 128 + (lane >> 4) * 4;
  float xr_[8][4];
#pragma unroll
  for (int m = 0; m < 8; ++m)
#pragma unroll
    for (int j = 0; j < 4; ++j)
      xr_[m][j] = xs[row0 + m * 16 + j];
#pragma unroll
  for (int n = 0; n < 4; ++n) {
    int ng = col0 + n * 16;
    float sc = scale[ng];
    float bi = bias[ng];
#pragma unroll
    for (int m = 0; m < 8; ++m) {
      int rg = row0 + m * 16;
#pragma unroll
      for (int j = 0; j < 4; ++j)
        __builtin_nontemporal_store((float)acc[m][n][j] * (xr_[m][j] * sc) + bi,
                                    &C[(size_t)(rg + j) * NDIM + ng]);
    }
  }
}

// ---------------- fallback (only if d_ws is too small) ----------------

__global__ void naive_kernel(const float* __restrict__ x, const int* __restrict__ w,
                             const float* __restrict__ scale, const float* __restrict__ bias,
                             float* __restrict__ out)
{
  int n = blockIdx.x * blockDim.x + threadIdx.x;
  int m = blockIdx.y;
  if (n >= NDIM) return;
  const float* xr = x + (size_t)m * KDIM;
  const int* wrow = w + (size_t)n * KDIM;
  float s = 0.f;
  for (int k = 0; k < KDIM; ++k) s += xr[k] * (float)wrow[k];
  out[(size_t)m * NDIM + n] = s * scale[n] + bias[n];
}

// ---------------- launcher ----------------

extern "C" void kernel_launch(void* const* d_in, const int* in_sizes, int n_in,
                              void* d_out, int out_size, void* d_ws, size_t ws_size,
                              hipStream_t stream) {
  const float* x      = (const float*)d_in[0];
  const int*   w8     = (const int*)d_in[1];
  const float* wscale = (const float*)d_in[2];
  const float* bias   = (const float*)d_in[3];
  float* out = (float*)d_out;

  size_t aq = (size_t)MDIM * KDIM;   // 33.5 MB i8
  size_t bq = (size_t)NDIM * KDIM;   // 45.1 MB i8
  size_t xb = (size_t)MDIM * 4;      // 32 KB scales

  if (ws_size >= aq + bq + xb) {
    char* Aq = (char*)d_ws;
    char* Bq = (char*)d_ws + aq;
    float* xsp = (float*)((char*)d_ws + aq + bq);
    quant_x_kernel<<<MDIM, 256, 0, stream>>>(x, (int*)Aq, xsp);
    cvt_w_kernel<<<2048, 256, 0, stream>>>(w8, (int*)Bq, NDIM * KDIM / 4);
    gemm_i8_kernel<<<(MDIM / BM) * (NDIM / BN), 512, 0, stream>>>(
        Aq, Bq, xsp, wscale, bias, out);
  } else {
    naive_kernel<<<dim3((NDIM + 255) / 256, MDIM), 256, 0, stream>>>(x, w8, wscale, bias, out);
  }
}

// Round 9
// 468.397 us; speedup vs baseline: 1.0703x; 1.0504x over previous
//
#include <hip/hip_runtime.h>
#include <hip/hip_bf16.h>

// Int8Linear: out[B,T,OUT] = x[B,T,IN] @ (w_int8*scale)^T + bias
// M = B*T = 8192, N = OUT = 11008, K = IN = 4096
// Full-int8: x per-token absmax-quantized, W exact i8, mfma_i32_16x16x64_i8,
// exact i32 accum, epilogue acc*xs[m]*wscale[n]+bias.
// R9: R6 kernel byte-identical EXCEPT block->tile mapping: 8x4 supertiles
// (32 co-resident blocks share 8 A + 4 B panels = 12 MB, near-L2/XCD) to
// lift the measured ~6.3 TB/s staging-delivery cap (R5-R8 invariant:
// 32KB/tile / 3160cyc = 10.4 B/cyc/CU = device copy ceiling).
#define MDIM 8192
#define NDIM 11008
#define KDIM 4096

#define BM 256
#define BN 256
#define BK 64
#define NT (KDIM / BK)   // 64 K-tiles

typedef __attribute__((ext_vector_type(4))) int int4v;

// ---------------- x quantization: per-token absmax -> i8 ----------------

__global__ __launch_bounds__(256) void quant_x_kernel(const float* __restrict__ x,
                                                      int* __restrict__ q,
                                                      float* __restrict__ xs) {
  int row = blockIdx.x;
  int tid = threadIdx.x;
  const float4* xr = (const float4*)(x + (size_t)row * KDIM);
  float4 v[4];
  float amax = 0.f;
#pragma unroll
  for (int i = 0; i < 4; ++i) {
    v[i] = xr[tid + i * 256];
    amax = fmaxf(amax, fmaxf(fmaxf(fabsf(v[i].x), fabsf(v[i].y)),
                             fmaxf(fabsf(v[i].z), fabsf(v[i].w))));
  }
#pragma unroll
  for (int off = 32; off; off >>= 1)
    amax = fmaxf(amax, __shfl_xor(amax, off));
  __shared__ float smax[4];
  if ((tid & 63) == 0) smax[tid >> 6] = amax;
  __syncthreads();
  amax = fmaxf(fmaxf(smax[0], smax[1]), fmaxf(smax[2], smax[3]));
  amax = fmaxf(amax, 1e-20f);
  float inv = 127.f / amax;
  if (tid == 0) xs[row] = amax * (1.f / 127.f);
  int* qr = q + (size_t)row * (KDIM / 4);
#pragma unroll
  for (int i = 0; i < 4; ++i) {
    int a = (int)rintf(v[i].x * inv) & 255;
    int b = (int)rintf(v[i].y * inv) & 255;
    int c = (int)rintf(v[i].z * inv) & 255;
    int d = (int)rintf(v[i].w * inv);
    qr[tid + i * 256] = a | (b << 8) | (c << 16) | (d << 24);
  }
}

// ---------------- W pack: int32 -> i8 (exact) ----------------

__global__ void cvt_w_kernel(const int* __restrict__ w, int* __restrict__ q, int n) {
  int stride = gridDim.x * blockDim.x;
  for (int i = blockIdx.x * blockDim.x + threadIdx.x; i < n; i += stride) {
    int4v v = *(const int4v*)(w + (size_t)i * 4);
    q[i] = (v.x & 255) | ((v.y & 255) << 8) | ((v.z & 255) << 16) | (v.w << 24);
  }
}

// ---------------- 256x256 int8 MFMA GEMM (ring-4, R6 body) ------
// LDS: per operand [4-ring][256 rows][64 B] = 64 KB; total 128 KB.
// Tile = {12 ds_read_b128, 2 MFMA half-clusters (16 each), stage A+B of T+2,
//         vmcnt(4), 1 barrier}.

#define SBARR() __builtin_amdgcn_sched_barrier(0)
#define BARR()  __builtin_amdgcn_s_barrier()
#define VMW_(n) asm volatile("s_waitcnt vmcnt(" #n ")" ::: "memory")
#define VMW(n)  VMW_(n)

#define GLL(SRC, DST) \
  __builtin_amdgcn_global_load_lds( \
      (const __attribute__((address_space(1))) void*)(SRC), \
      (__attribute__((address_space(3))) void*)(DST), 16, 0, 0)

// stage one operand's K-tile T (16KB): 2 loads/thread, linear LDS dest
#define STAGE(GSRC, LBASE, BUFI, T) do { \
    const char* _s = (GSRC) + (T) * 64; \
    GLL(_s, (LBASE) + (BUFI) * 16384 + w * 1024); \
    GLL(_s + rstep, (LBASE) + (BUFI) * 16384 + w * 1024 + 8192); \
  } while (0)

// swizzled fragment read (16B = 16 i8 along K for one row)
#define RD(LB, BUFI, ROW) \
  (*(const int4v*)((LB) + (BUFI) * 16384 + (ROW) * 64 + kbs))

#define MFMA16(AF, MOFF) do { \
    _Pragma("unroll") for (int mi = 0; mi < 4; ++mi) \
    _Pragma("unroll") for (int ni = 0; ni < 4; ++ni) \
      acc[(MOFF) + mi][ni] = __builtin_amdgcn_mfma_i32_16x16x64_i8( \
          af[mi], bf[ni], acc[(MOFF) + mi][ni], 0, 0, 0); \
  } while (0)

// One K-tile. B_ = ring slot (compile-time), SD = stage T+2, VN = vmcnt arg,
// TAIL = last tile (skip trailing wait+barrier).
#define KT(T, B_, SD, VN, TAIL) do { \
    _Pragma("unroll") for (int ni = 0; ni < 4; ++ni) bf[ni] = RD(ldsB, B_, brow0 + ni * 16); \
    _Pragma("unroll") for (int mi = 0; mi < 4; ++mi) af[mi] = RD(ldsA, B_, arow0 + mi * 16); \
    if (SD) STAGE(gAs, ldsA, ((B_) + 2) & 3, (T) + 2); \
    SBARR(); \
    __builtin_amdgcn_s_setprio(1); MFMA16(af, 0); __builtin_amdgcn_s_setprio(0); \
    SBARR(); \
    _Pragma("unroll") for (int mi = 0; mi < 4; ++mi) af[mi] = RD(ldsA, B_, arow0 + 64 + mi * 16); \
    if (SD) STAGE(gBs, ldsB, ((B_) + 2) & 3, (T) + 2); \
    SBARR(); \
    __builtin_amdgcn_s_setprio(1); MFMA16(af, 4); __builtin_amdgcn_s_setprio(0); \
    SBARR(); \
    if (!(TAIL)) { VMW(VN); BARR(); SBARR(); } \
  } while (0)

__global__ __launch_bounds__(512, 2) void gemm_i8_kernel(
    const char* __restrict__ A,
    const char* __restrict__ Bt,
    const float* __restrict__ xs,
    const float* __restrict__ scale,
    const float* __restrict__ bias,
    float* __restrict__ C)
{
  __shared__ __attribute__((aligned(16))) char As[4][256][64];  // 64 KB
  __shared__ __attribute__((aligned(16))) char Bs[4][256][64];  // 64 KB

  // grid = 32*43 = 1376 = 8*172
  int bid = blockIdx.x;
  int cpx = gridDim.x >> 3;                 // 172
  int swz = (bid & 7) * cpx + (bid >> 3);   // bijective XCD swizzle
  // R9: 8x4 supertile order (bijective; ragged last col 8x3).
  // 344 = 8 brows * 43 bcols per srow-band; 32 co-resident blocks = one
  // supertile sharing 8 A panels + 4 B panels (12 MB).
  int srow = swz / 344;
  int rem  = swz - srow * 344;
  int scol, q;
  if (rem < 320) { scol = rem >> 5; q = rem & 31; }
  else           { scol = 10;       q = rem - 320; }
  int brow = (srow * 8 + (q & 7)) * BM;
  int bcol = (scol * 4 + (q >> 3)) * BN;

  int tid  = threadIdx.x;
  int lane = tid & 63;
  int w    = tid >> 6;
  int wr   = (w >> 2) & 1;   // M-wave (2)
  int wc   = w & 3;          // N-wave (4)

  int ra = lane & 15;                         // fragment row within 16
  int kb = (lane >> 4) * 16;                  // byte offset along K (64B row)
  int kbs = kb ^ (((ra >> 1) & 3) << 4);      // proven 0-conflict swizzle

  int arow0 = wr * 128 + ra;                  // wave's A base row + frag row
  int brow0 = wc * 64 + ra;                   // wave's B base row + frag row

  // staging: thread granule g = w*64+lane -> (row srow, dst granule lane&3);
  // inverse-swizzled source k-granule (lane-constant)
  int srw = w * 16 + (lane >> 2);
  int csrc = (lane & 3) ^ ((lane >> 3) & 3);
  const char* gAs = A  + (size_t)(brow + srw) * KDIM + csrc * 16;
  const char* gBs = Bt + (size_t)(bcol + srw) * KDIM + csrc * 16;
  const size_t rstep = (size_t)128 * KDIM;

  char* ldsA = &As[0][0][0];
  char* ldsB = &Bs[0][0][0];

  int4v acc[8][4] = {};
  int4v af[4], bf[4];

  // prologue: tiles 0,1 staged into ring slots 0,1; drain tile 0
  STAGE(gAs, ldsA, 0, 0);  STAGE(gBs, ldsB, 0, 0);
  STAGE(gAs, ldsA, 1, 1);  STAGE(gBs, ldsB, 1, 1);
  VMW(4); BARR(); SBARR();

  // steady: tiles 0..61 stage T+2; invariant entering tile T: 4 loads
  // outstanding = (T+1).A + (T+1).B
  for (int t = 0; t < 56; t += 4) {
    KT(t,     0, 1, 4, 0);
    KT(t + 1, 1, 1, 4, 0);
    KT(t + 2, 2, 1, 4, 0);
    KT(t + 3, 3, 1, 4, 0);
  }
  KT(56, 0, 1, 4, 0);
  KT(57, 1, 1, 4, 0);
  KT(58, 2, 1, 4, 0);
  KT(59, 3, 1, 4, 0);
  KT(60, 0, 1, 4, 0);
  KT(61, 1, 1, 4, 0);
  KT(62, 2, 0, 0, 0);   // no stage; drain tile 63
  KT(63, 3, 0, 0, 1);   // last tile

  // epilogue: C/D layout col = lane&15, row = (lane>>4)*4 + reg (dtype-indep)
  // non-temporal stores: write stream must not churn L2/L3
  int col0 = bcol + wc * 64 + ra;
  int row0 = brow + wr * 128 + (lane >> 4) * 4;
  float xr_[8][4];
#pragma unroll
  for (int m = 0; m < 8; ++m)
#pragma unroll
    for (int j = 0; j < 4; ++j)
      xr_[m][j] = xs[row0 + m * 16 + j];
#pragma unroll
  for (int n = 0; n < 4; ++n) {
    int ng = col0 + n * 16;
    float sc = scale[ng];
    float bi = bias[ng];
#pragma unroll
    for (int m = 0; m < 8; ++m) {
      int rg = row0 + m * 16;
#pragma unroll
      for (int j = 0; j < 4; ++j)
        __builtin_nontemporal_store((float)acc[m][n][j] * (xr_[m][j] * sc) + bi,
                                    &C[(size_t)(rg + j) * NDIM + ng]);
    }
  }
}

// ---------------- fallback (only if d_ws is too small) ----------------

__global__ void naive_kernel(const float* __restrict__ x, const int* __restrict__ w,
                             const float* __restrict__ scale, const float* __restrict__ bias,
                             float* __restrict__ out)
{
  int n = blockIdx.x * blockDim.x + threadIdx.x;
  int m = blockIdx.y;
  if (n >= NDIM) return;
  const float* xr = x + (size_t)m * KDIM;
  const int* wrow = w + (size_t)n * KDIM;
  float s = 0.f;
  for (int k = 0; k < KDIM; ++k) s += xr[k] * (float)wrow[k];
  out[(size_t)m * NDIM + n] = s * scale[n] + bias[n];
}

// ---------------- launcher ----------------

extern "C" void kernel_launch(void* const* d_in, const int* in_sizes, int n_in,
                              void* d_out, int out_size, void* d_ws, size_t ws_size,
                              hipStream_t stream) {
  const float* x      = (const float*)d_in[0];
  const int*   w8     = (const int*)d_in[1];
  const float* wscale = (const float*)d_in[2];
  const float* bias   = (const float*)d_in[3];
  float* out = (float*)d_out;

  size_t aq = (size_t)MDIM * KDIM;   // 33.5 MB i8
  size_t bq = (size_t)NDIM * KDIM;   // 45.1 MB i8
  size_t xb = (size_t)MDIM * 4;      // 32 KB scales

  if (ws_size >= aq + bq + xb) {
    char* Aq = (char*)d_ws;
    char* Bq = (char*)d_ws + aq;
    float* xsp = (float*)((char*)d_ws + aq + bq);
    quant_x_kernel<<<MDIM, 256, 0, stream>>>(x, (int*)Aq, xsp);
    cvt_w_kernel<<<2048, 256, 0, stream>>>(w8, (int*)Bq, NDIM * KDIM / 4);
    gemm_i8_kernel<<<(MDIM / BM) * (NDIM / BN), 512, 0, stream>>>(
        Aq, Bq, xsp, wscale, bias, out);
  } else {
    naive_kernel<<<dim3((NDIM + 255) / 256, MDIM), 256, 0, stream>>>(x, w8, wscale, bias, out);
  }
}